// Round 9
// baseline (134.692 us; speedup 1.0000x reference)
//
#include <hip/hip_runtime.h>

using bf16 = __bf16;
using bf16x4 = __attribute__((ext_vector_type(4))) __bf16;
using bf16x8 = __attribute__((ext_vector_type(8))) __bf16;
using floatx4 = __attribute__((ext_vector_type(4))) float;

#define D_MODEL 512
#define S_LEN 2048
#define HD 64
#define NH 8
#define M_TOT 4096   // B * S
#define QSCALE 0.18033688f       // 0.125 * log2(e), folded into Q

__device__ __forceinline__ bf16x8 ld8(const bf16* p) {
    return *reinterpret_cast<const bf16x8*>(p);
}
__device__ __forceinline__ void gl_lds16(const bf16* g, bf16* l) {
    __builtin_amdgcn_global_load_lds(
        (const __attribute__((address_space(1))) void*)g,
        (__attribute__((address_space(3))) void*)l, 16, 0, 0);
}

// ---------------- prep: z<4 -> transpose W[z] (fp32->bf16, WT[n][k]); z==4 -> cvt X ----------------
__global__ __launch_bounds__(256) void prep(const float* __restrict__ w0,
                                            const float* __restrict__ w1,
                                            const float* __restrict__ w2,
                                            const float* __restrict__ w3,
                                            const float* __restrict__ X,
                                            bf16* __restrict__ WT,
                                            bf16* __restrict__ Xb) {
    int z = blockIdx.z;
    if (z == 4) {
        int i = (blockIdx.x * 256 + threadIdx.x) * 8;
        float4 a = *reinterpret_cast<const float4*>(X + i);
        float4 b = *reinterpret_cast<const float4*>(X + i + 4);
        bf16x8 o;
        o[0] = (bf16)a.x; o[1] = (bf16)a.y; o[2] = (bf16)a.z; o[3] = (bf16)a.w;
        o[4] = (bf16)b.x; o[5] = (bf16)b.y; o[6] = (bf16)b.z; o[7] = (bf16)b.w;
        *reinterpret_cast<bf16x8*>(Xb + i) = o;
        return;
    }
    if (blockIdx.x >= 256) return;
    __shared__ float t[32][33];
    const float* in = z == 0 ? w0 : z == 1 ? w1 : z == 2 ? w2 : w3;
    bf16* o = WT + (size_t)z * D_MODEL * D_MODEL;
    int x = threadIdx.x & 31;
    int y = threadIdx.x >> 5;
    int k0 = (blockIdx.x & 15) * 32, n0 = (blockIdx.x >> 4) * 32;
    for (int r = y; r < 32; r += 8) t[r][x] = in[(size_t)(k0 + r) * D_MODEL + n0 + x];
    __syncthreads();
    for (int r = y; r < 32; r += 8) o[(size_t)(n0 + r) * D_MODEL + k0 + x] = (bf16)t[x][r];
}

// ---------------- fused QKV projection: X[4096x512] @ [Wq|Wk|Wv] (N=1536) ----------------
// 2-phase double-buffered pipeline: stage(t+1) issued before compute(t); one barrier/iter.
__global__ __launch_bounds__(256) void gemm_qkvf(const bf16* __restrict__ X,
                                                 const bf16* __restrict__ WT,
                                                 bf16* __restrict__ qk,
                                                 bf16* __restrict__ VT) {
    __shared__ __align__(16) bf16 As[2][64 * 64];
    __shared__ __align__(16) bf16 Bs[2][64 * 64];
    int lane = threadIdx.x & 63, wave = threadIdx.x >> 6;
    int l15 = lane & 15, quad = lane >> 4;
    int m0 = blockIdx.x * 64;
    int n0 = blockIdx.y * 64;
    int z = n0 >> 9;
    int h = (n0 >> 6) & 7;
    int wm = (wave & 1) * 32, wn = (wave >> 1) * 32;
    float oscale = (z == 0) ? QSCALE : 1.0f;

    int sr = lane >> 3;
    int sc = (lane & 7) ^ sr;
    const bf16* gA = X  + (size_t)(m0 + wave * 16 + sr) * D_MODEL + sc * 8;
    const bf16* gB = WT + (size_t)(n0 + wave * 16 + sr) * D_MODEL + sc * 8;
    int ldsOff = (wave * 16) * 64;
    int rx = l15 & 7;

    // prologue: stage k0=0 into buffer 0
    gl_lds16(gA, &As[0][ldsOff]);
    gl_lds16(gA + (size_t)8 * D_MODEL, &As[0][ldsOff + 8 * 64]);
    gl_lds16(gB, &Bs[0][ldsOff]);
    gl_lds16(gB + (size_t)8 * D_MODEL, &Bs[0][ldsOff + 8 * 64]);
    __syncthreads();

    floatx4 acc[2][2] = {};
    int cur = 0;
    for (int k0 = 0; k0 < D_MODEL; k0 += 64) {
        if (k0 + 64 < D_MODEL) {
            gl_lds16(gA + k0 + 64, &As[cur ^ 1][ldsOff]);
            gl_lds16(gA + (size_t)8 * D_MODEL + k0 + 64, &As[cur ^ 1][ldsOff + 8 * 64]);
            gl_lds16(gB + k0 + 64, &Bs[cur ^ 1][ldsOff]);
            gl_lds16(gB + (size_t)8 * D_MODEL + k0 + 64, &Bs[cur ^ 1][ldsOff + 8 * 64]);
        }
        bf16x8 af[2][2], bfr[2][2];
        #pragma unroll
        for (int mt = 0; mt < 2; mt++)
            #pragma unroll
            for (int kh = 0; kh < 2; kh++)
                af[mt][kh] = ld8(&As[cur][(wm + mt * 16 + l15) * 64 + (((quad + 4 * kh) ^ rx)) * 8]);
        #pragma unroll
        for (int nt = 0; nt < 2; nt++)
            #pragma unroll
            for (int kh = 0; kh < 2; kh++)
                bfr[nt][kh] = ld8(&Bs[cur][(wn + nt * 16 + l15) * 64 + (((quad + 4 * kh) ^ rx)) * 8]);
        #pragma unroll
        for (int mt = 0; mt < 2; mt++)
            #pragma unroll
            for (int nt = 0; nt < 2; nt++) {
                acc[mt][nt] = __builtin_amdgcn_mfma_f32_16x16x32_bf16(af[mt][0], bfr[nt][0], acc[mt][nt], 0, 0, 0);
                acc[mt][nt] = __builtin_amdgcn_mfma_f32_16x16x32_bf16(af[mt][1], bfr[nt][1], acc[mt][nt], 0, 0, 0);
            }
        __syncthreads();   // drains vmcnt: prefetch landed; all waves done with buf[cur]
        cur ^= 1;
    }

    if (z < 2) {
        bf16* dst = qk + (size_t)z * M_TOT * HD * NH;
        #pragma unroll
        for (int mt = 0; mt < 2; mt++)
            #pragma unroll
            for (int nt = 0; nt < 2; nt++)
                #pragma unroll
                for (int r = 0; r < 4; r++) {
                    int m = m0 + wm + mt * 16 + quad * 4 + r;
                    int n = wn + nt * 16 + l15;
                    int b = m >> 11, s = m & 2047;
                    dst[((size_t)(b * NH + h) * S_LEN + s) * HD + n] = (bf16)(acc[mt][nt][r] * oscale);
                }
    } else {
        #pragma unroll
        for (int mt = 0; mt < 2; mt++)
            #pragma unroll
            for (int nt = 0; nt < 2; nt++) {
                int m = m0 + wm + mt * 16 + quad * 4;
                int d = wn + nt * 16 + l15;
                int b = m >> 11, s = m & 2047;
                bf16x4 pk;
                pk[0] = (bf16)acc[mt][nt][0]; pk[1] = (bf16)acc[mt][nt][1];
                pk[2] = (bf16)acc[mt][nt][2]; pk[3] = (bf16)acc[mt][nt][3];
                *reinterpret_cast<bf16x4*>(&VT[((size_t)(b * NH + h) * HD + d) * S_LEN + s]) = pk;
            }
    }
}

// ---------------- per-tile attention body (inlined 2x per iteration) ----------------
// P-transform via xor-32 half-cross only (8 shfl_xor + 8 selects, replaces 16 dynamic
// bpermute). Key-axis is consumed in a fixed permutation; V is read in the SAME permuted
// 4-column groups (16x ds_read_b64), so the PV contraction is unchanged.
// pb[0] keys: q0{0-3,8-11} q1{4-7,12-15} q2{32-35,40-43} q3{36-39,44-47}
// pb[1] keys: q0{16-19,24-27} q1{20-23,28-31} q2{48-51,56-59} q3{52-55,60-63}
__device__ __forceinline__ void attn_tile(const bf16* __restrict__ Klc,
                                          const bf16* __restrict__ Vlc,
                                          bf16x8 qf0, bf16x8 qf1,
                                          int l15, int quad, int rx, bool low,
                                          floatx4 (&O)[4], float& l_i) {
    // S^T: A = K-frag [m=key][k=d], B = Q-frag [k=d][n=q]
    floatx4 sc4[4];
    #pragma unroll
    for (int nt = 0; nt < 4; nt++) {
        floatx4 z = {};
        bf16x8 a0 = ld8(&Klc[(nt * 16 + l15) * 64 + (quad ^ rx) * 8]);
        bf16x8 a1 = ld8(&Klc[(nt * 16 + l15) * 64 + ((quad + 4) ^ rx) * 8]);
        z = __builtin_amdgcn_mfma_f32_16x16x32_bf16(a0, qf0, z, 0, 0, 0);
        z = __builtin_amdgcn_mfma_f32_16x16x32_bf16(a1, qf1, z, 0, 0, 0);
        sc4[nt] = z;    // key = nt*16+quad*4+r, qcol = l15
    }

    // p = exp2(s); pack per-nt into bf16x4 (as int2); accumulate l in-lane
    int2 pq[4];
    #pragma unroll
    for (int nt = 0; nt < 4; nt++) {
        bf16x4 pk;
        #pragma unroll
        for (int r = 0; r < 4; r++) {
            float p = exp2f(sc4[nt][r]);
            l_i += p;
            pk[r] = (bf16)p;
        }
        pq[nt] = __builtin_bit_cast(int2, pk);
    }

    // half-cross: P0/P1 = own(low)/partner-pq[2,3](high); P2/P3 = partner-pq[0,1](low)/own(high)
    int f0x = __shfl_xor(pq[0].x, 32, 64);
    int f0y = __shfl_xor(pq[0].y, 32, 64);
    int f1x = __shfl_xor(pq[1].x, 32, 64);
    int f1y = __shfl_xor(pq[1].y, 32, 64);
    int f2x = __shfl_xor(pq[2].x, 32, 64);
    int f2y = __shfl_xor(pq[2].y, 32, 64);
    int f3x = __shfl_xor(pq[3].x, 32, 64);
    int f3y = __shfl_xor(pq[3].y, 32, 64);
    int P0x = low ? pq[0].x : f2x;
    int P0y = low ? pq[0].y : f2y;
    int P2x = low ? f0x : pq[2].x;
    int P2y = low ? f0y : pq[2].y;
    int P1x = low ? pq[1].x : f3x;
    int P1y = low ? pq[1].y : f3y;
    int P3x = low ? f1x : pq[3].x;
    int P3y = low ? f1y : pq[3].y;
    int4 w0 = {P0x, P0y, P2x, P2y};
    int4 w1 = {P1x, P1y, P3x, P3y};
    bf16x8 pb0 = __builtin_bit_cast(bf16x8, w0);
    bf16x8 pb1 = __builtin_bit_cast(bf16x8, w1);

    // O^T += V^T P^T : A = VT-frag [m=d][k(permuted keys)], read in matching 4-col groups
    #pragma unroll
    for (int nt = 0; nt < 4; nt++) {
        int row = (nt * 16 + l15) * 64;
        #pragma unroll
        for (int h2 = 0; h2 < 2; h2++) {
            int g1 = (quad & 1) + ((quad >> 1) << 3) + (h2 << 2);  // 4-col group; g2 = g1+2
            bf16x4 va = *reinterpret_cast<const bf16x4*>(
                &Vlc[row + ((g1 >> 1) ^ rx) * 8 + (g1 & 1) * 4]);
            bf16x4 vb = *reinterpret_cast<const bf16x4*>(
                &Vlc[row + (((g1 + 2) >> 1) ^ rx) * 8 + (g1 & 1) * 4]);
            int2 ia = __builtin_bit_cast(int2, va);
            int2 ib = __builtin_bit_cast(int2, vb);
            int4 wv = {ia.x, ia.y, ib.x, ib.y};
            bf16x8 vA = __builtin_bit_cast(bf16x8, wv);
            O[nt] = __builtin_amdgcn_mfma_f32_16x16x32_bf16(vA, h2 ? pb1 : pb0, O[nt], 0, 0, 0);
        }
    }
}

// ---------------- flash attention, single pass, KBLK=128 (2 K-tiles per barrier) ----------------
// grid (32, 16); block 256 = 4 waves; each wave owns 16 queries (Q-tile 64/block).
// 4 LDS buffers (2 iter x 2 tiles, 64KB); ONE barrier per 128 keys.
// Normalizes by 1/l in-kernel, writes A-operand-ready bf16 Ob[4096][512].
__global__ __launch_bounds__(256, 2) void attn_full(const bf16* __restrict__ qg,
                                                    const bf16* __restrict__ kg,
                                                    const bf16* __restrict__ vt,
                                                    bf16* __restrict__ Ob) {
    __shared__ __align__(16) bf16 Kl[2][2][64 * 64];  // [iterbuf][tile][key][d]
    __shared__ __align__(16) bf16 Vl[2][2][64 * 64];  // [iterbuf][tile][d][key]
    int tid = threadIdx.x;
    int lane = tid & 63, wave = tid >> 6;
    int l15 = lane & 15, quad = lane >> 4;
    bool low = lane < 32;
    int bh = blockIdx.y;
    int q0 = blockIdx.x * 64;
    const bf16* qb = qg + (size_t)bh * S_LEN * HD;
    const bf16* kb = kg + (size_t)bh * S_LEN * HD;
    const bf16* vb = vt + (size_t)bh * HD * S_LEN;
    int q = q0 + wave * 16 + l15;
    bf16x8 qf0 = ld8(qb + (size_t)q * HD + quad * 8);   // B-frag, Q pre-scaled
    bf16x8 qf1 = ld8(qb + (size_t)q * HD + 32 + quad * 8);
    floatx4 O[4] = {};
    float l_i = 0.f;

    int sr = lane >> 3;
    int sc = (lane & 7) ^ sr;
    const bf16* gK = kb + (size_t)(wave * 16 + sr) * HD + sc * 8;
    const bf16* gV = vb + (size_t)(wave * 16 + sr) * S_LEN + sc * 8;
    int ldsOff = (wave * 16) * 64;
    int rx = l15 & 7;

    // prologue: stage iteration 0 (tiles k=0 and k=64) into iterbuf 0
    gl_lds16(gK, &Kl[0][0][ldsOff]);
    gl_lds16(gK + (size_t)8 * HD, &Kl[0][0][ldsOff + 8 * 64]);
    gl_lds16(gV, &Vl[0][0][ldsOff]);
    gl_lds16(gV + (size_t)8 * S_LEN, &Vl[0][0][ldsOff + 8 * 64]);
    gl_lds16(gK + (size_t)64 * HD, &Kl[0][1][ldsOff]);
    gl_lds16(gK + (size_t)72 * HD, &Kl[0][1][ldsOff + 8 * 64]);
    gl_lds16(gV + 64, &Vl[0][1][ldsOff]);
    gl_lds16(gV + (size_t)8 * S_LEN + 64, &Vl[0][1][ldsOff + 8 * 64]);
    __syncthreads();

    int cur = 0;
    for (int kt = 0; kt < S_LEN; kt += 128) {
        if (kt + 128 < S_LEN) {
            int kn = kt + 128;
            gl_lds16(gK + (size_t)kn * HD, &Kl[cur ^ 1][0][ldsOff]);
            gl_lds16(gK + (size_t)(kn + 8) * HD, &Kl[cur ^ 1][0][ldsOff + 8 * 64]);
            gl_lds16(gV + kn, &Vl[cur ^ 1][0][ldsOff]);
            gl_lds16(gV + (size_t)8 * S_LEN + kn, &Vl[cur ^ 1][0][ldsOff + 8 * 64]);
            gl_lds16(gK + (size_t)(kn + 64) * HD, &Kl[cur ^ 1][1][ldsOff]);
            gl_lds16(gK + (size_t)(kn + 72) * HD, &Kl[cur ^ 1][1][ldsOff + 8 * 64]);
            gl_lds16(gV + kn + 64, &Vl[cur ^ 1][1][ldsOff]);
            gl_lds16(gV + (size_t)8 * S_LEN + kn + 64, &Vl[cur ^ 1][1][ldsOff + 8 * 64]);
        }

        attn_tile(Kl[cur][0], Vl[cur][0], qf0, qf1, l15, quad, rx, low, O, l_i);
        attn_tile(Kl[cur][1], Vl[cur][1], qf0, qf1, l15, quad, rx, low, O, l_i);

        __syncthreads();   // drains vmcnt: prefetch landed; all waves done with iterbuf[cur]
        cur ^= 1;
    }

    l_i += __shfl_xor(l_i, 16, 64);
    l_i += __shfl_xor(l_i, 32, 64);
    float inv = 1.f / l_i;

    int b = bh >> 3, h = bh & 7;
    size_t obase = ((size_t)(b * S_LEN + q)) * D_MODEL + h * HD;
    #pragma unroll
    for (int nt = 0; nt < 4; nt++) {
        bf16x4 hv;
        hv[0] = (bf16)(O[nt][0] * inv); hv[1] = (bf16)(O[nt][1] * inv);
        hv[2] = (bf16)(O[nt][2] * inv); hv[3] = (bf16)(O[nt][3] * inv);
        *reinterpret_cast<bf16x4*>(&Ob[obase + nt * 16 + quad * 4]) = hv;
    }
}

// ---------------- output projection: Ob[4096x512] @ WoT -> out FP32 (pure GEMM, 2-phase) ----------------
__global__ __launch_bounds__(256) void gemm_out(const bf16* __restrict__ Ob,
                                                const bf16* __restrict__ WoT,
                                                float* __restrict__ out) {
    __shared__ __align__(16) bf16 As[2][64 * 64];
    __shared__ __align__(16) bf16 Bs[2][64 * 64];
    int lane = threadIdx.x & 63, wave = threadIdx.x >> 6;
    int l15 = lane & 15, quad = lane >> 4;
    int m0 = blockIdx.x * 64;
    int n0 = blockIdx.y * 64;
    int wm = (wave & 1) * 32, wn = (wave >> 1) * 32;

    int sr = lane >> 3;
    int sc = (lane & 7) ^ sr;
    const bf16* gA = Ob  + (size_t)(m0 + wave * 16 + sr) * D_MODEL + sc * 8;
    const bf16* gB = WoT + (size_t)(n0 + wave * 16 + sr) * D_MODEL + sc * 8;
    int ldsOff = (wave * 16) * 64;
    int rx = l15 & 7;

    gl_lds16(gA, &As[0][ldsOff]);
    gl_lds16(gA + (size_t)8 * D_MODEL, &As[0][ldsOff + 8 * 64]);
    gl_lds16(gB, &Bs[0][ldsOff]);
    gl_lds16(gB + (size_t)8 * D_MODEL, &Bs[0][ldsOff + 8 * 64]);
    __syncthreads();

    floatx4 acc[2][2] = {};
    int cur = 0;
    for (int k0 = 0; k0 < D_MODEL; k0 += 64) {
        if (k0 + 64 < D_MODEL) {
            gl_lds16(gA + k0 + 64, &As[cur ^ 1][ldsOff]);
            gl_lds16(gA + (size_t)8 * D_MODEL + k0 + 64, &As[cur ^ 1][ldsOff + 8 * 64]);
            gl_lds16(gB + k0 + 64, &Bs[cur ^ 1][ldsOff]);
            gl_lds16(gB + (size_t)8 * D_MODEL + k0 + 64, &Bs[cur ^ 1][ldsOff + 8 * 64]);
        }
        bf16x8 af[2][2], bfr[2][2];
        #pragma unroll
        for (int mt = 0; mt < 2; mt++)
            #pragma unroll
            for (int kh = 0; kh < 2; kh++)
                af[mt][kh] = ld8(&As[cur][(wm + mt * 16 + l15) * 64 + (((quad + 4 * kh) ^ rx)) * 8]);
        #pragma unroll
        for (int nt = 0; nt < 2; nt++)
            #pragma unroll
            for (int kh = 0; kh < 2; kh++)
                bfr[nt][kh] = ld8(&Bs[cur][(wn + nt * 16 + l15) * 64 + (((quad + 4 * kh) ^ rx)) * 8]);
        #pragma unroll
        for (int mt = 0; mt < 2; mt++)
            #pragma unroll
            for (int nt = 0; nt < 2; nt++) {
                acc[mt][nt] = __builtin_amdgcn_mfma_f32_16x16x32_bf16(af[mt][0], bfr[nt][0], acc[mt][nt], 0, 0, 0);
                acc[mt][nt] = __builtin_amdgcn_mfma_f32_16x16x32_bf16(af[mt][1], bfr[nt][1], acc[mt][nt], 0, 0, 0);
            }
        __syncthreads();
        cur ^= 1;
    }

    #pragma unroll
    for (int mt = 0; mt < 2; mt++)
        #pragma unroll
        for (int nt = 0; nt < 2; nt++)
            #pragma unroll
            for (int r = 0; r < 4; r++) {
                int m = m0 + wm + mt * 16 + quad * 4 + r;
                int n = n0 + wn + nt * 16 + l15;
                out[(size_t)m * D_MODEL + n] = acc[mt][nt][r];
            }
}

extern "C" void kernel_launch(void* const* d_in, const int* in_sizes, int n_in,
                              void* d_out, int out_size, void* d_ws, size_t ws_size,
                              hipStream_t stream) {
    const float* X  = (const float*)d_in[0];
    const float* Wq = (const float*)d_in[1];
    const float* Wk = (const float*)d_in[2];
    const float* Wv = (const float*)d_in[3];
    const float* Wo = (const float*)d_in[4];
    float* out = (float*)d_out;
    bf16* ws  = (bf16*)d_ws;

    bf16* Xb  = ws;                                   // 2M bf16
    bf16* WT  = Xb + (size_t)M_TOT * D_MODEL;         // 1M (4 matrices)
    bf16* qk  = WT + (size_t)4 * D_MODEL * D_MODEL;   // 4M : q,k slabs [bh][s][d]
    bf16* VT  = qk + (size_t)2 * M_TOT * D_MODEL;     // 2M : [bh][d][s]
    bf16* Ob  = VT + (size_t)M_TOT * D_MODEL;         // 2M : [b][s][h*64+d]

    prep<<<dim3(1024, 1, 5), 256, 0, stream>>>(Wq, Wk, Wv, Wo, X, WT, Xb);
    gemm_qkvf<<<dim3(64, 24), 256, 0, stream>>>(Xb, WT, qk, VT);
    attn_full<<<dim3(32, 16), 256, 0, stream>>>(qk,
                                                qk + (size_t)M_TOT * D_MODEL,
                                                VT, Ob);
    gemm_out<<<dim3(64, 8), 256, 0, stream>>>(Ob,
                                              WT + (size_t)3 * D_MODEL * D_MODEL, out);
}